// Round 1
// baseline (5871.575 us; speedup 1.0000x reference)
//
#include <hip/hip_runtime.h>
#include <cstdint>
#include <climits>

#define NN 50000
#define EE 1600000
#define GG 512
#define NEG_SLOPE 0.2f

// ---------- helpers ----------
__device__ __forceinline__ int f2key(float f) {
    int i = __float_as_int(f);
    return i >= 0 ? i : (i ^ 0x7fffffff);
}
__device__ __forceinline__ float key2f(int k) {
    return __int_as_float(k >= 0 ? k : (k ^ 0x7fffffff));
}

// ---------- self-loop edge_attr (mean fill) ----------
__global__ void k_deg(const int* __restrict__ dst, float* __restrict__ deg) {
    int e = blockIdx.x * blockDim.x + threadIdx.x;
    if (e < EE) atomicAdd(&deg[dst[e]], 1.0f);
}

__global__ void k_loopacc(const int* __restrict__ dst, const float* __restrict__ ea,
                          float* __restrict__ loop_ea) {
    int t = blockIdx.x * blockDim.x + threadIdx.x;
    if (t < EE * 18) {
        int e = t / 18, c = t - e * 18;
        atomicAdd(&loop_ea[dst[e] * 18 + c], ea[t]);
    }
}

__global__ void k_loopdiv(float* __restrict__ loop_ea, const float* __restrict__ deg) {
    int t = blockIdx.x * blockDim.x + threadIdx.x;
    if (t < NN * 18) {
        int i = t / 18;
        loop_ea[t] /= fmaxf(deg[i], 1.0f);
    }
}

// ---------- fused dual node-linear: xl = X@Wl+bl ; xr = X@Wr+br ----------
__global__ void k_dual_linear(const float* __restrict__ X,
                              const float* __restrict__ Wl, const float* __restrict__ bl,
                              const float* __restrict__ Wr, const float* __restrict__ br,
                              float* __restrict__ xl, float* __restrict__ xr,
                              int Cin, int Cout) {
    int t = blockIdx.x * blockDim.x + threadIdx.x;
    if (t >= NN * Cout) return;
    int i = t / Cout, j = t - i * Cout;
    const float* xrow = X + (size_t)i * Cin;
    float al = bl[j], ar = br[j];
    for (int k = 0; k < Cin; k++) {
        float xv = xrow[k];
        al += xv * Wl[k * Cout + j];
        ar += xv * Wr[k * Cout + j];
    }
    xl[t] = al;
    xr[t] = ar;
}

// ---------- per-node init for softmax state ----------
__global__ void k_init_nodes(int* __restrict__ mkey, float* __restrict__ z) {
    int i = blockIdx.x * blockDim.x + threadIdx.x;
    if (i < NN) { mkey[i] = INT_MIN; z[i] = 0.0f; }
}

// ---------- edge scores: s_e = att . leakyrelu(xl[src]+xr[dst]+ea@We) ----------
template <int C>
__global__ void k_edge_score(const int* __restrict__ src, const int* __restrict__ dst,
                             const float* __restrict__ ea, const float* __restrict__ loop_ea,
                             const float* __restrict__ We, const float* __restrict__ att,
                             const float* __restrict__ xl, const float* __restrict__ xr,
                             float* __restrict__ s, int* __restrict__ mkey) {
    __shared__ float sWe[18 * C];
    __shared__ float sAtt[C];
    for (int t = threadIdx.x; t < 18 * C; t += blockDim.x) sWe[t] = We[t];
    for (int t = threadIdx.x; t < C; t += blockDim.x) sAtt[t] = att[t];
    __syncthreads();

    const int wavesPerBlock = blockDim.x >> 6;
    long wid = (long)blockIdx.x * wavesPerBlock + (threadIdx.x >> 6);
    int lane = threadIdx.x & 63;
    const int total = EE + NN;
    if (wid >= total) return;
    int e = (int)wid;

    int sIdx, dIdx;
    const float* eap;
    if (e < EE) { sIdx = src[e]; dIdx = dst[e]; eap = ea + (size_t)e * 18; }
    else        { sIdx = dIdx = e - EE;         eap = loop_ea + (size_t)(e - EE) * 18; }

    float eav[18];
#pragma unroll
    for (int k = 0; k < 18; k++) eav[k] = eap[k];

    float part = 0.0f;
#pragma unroll
    for (int c = lane; c < C; c += 64) {
        float acc = xl[(size_t)sIdx * C + c] + xr[(size_t)dIdx * C + c];
#pragma unroll
        for (int k = 0; k < 18; k++) acc += eav[k] * sWe[k * C + c];
        float h = acc > 0.0f ? acc : NEG_SLOPE * acc;
        part += sAtt[c] * h;
    }
    for (int off = 32; off; off >>= 1) part += __shfl_xor(part, off, 64);
    if (lane == 0) {
        s[e] = part;
        atomicMax(&mkey[dIdx], f2key(part));
    }
}

// ---------- exp(s - m[dst]) and z accumulation ----------
__global__ void k_expsum(const int* __restrict__ dst, const int* __restrict__ mkey,
                         float* __restrict__ s, float* __restrict__ z) {
    int e = blockIdx.x * blockDim.x + threadIdx.x;
    if (e >= EE + NN) return;
    int d = (e < EE) ? dst[e] : (e - EE);
    float m = key2f(mkey[d]);
    float w = expf(s[e] - m);
    s[e] = w;
    atomicAdd(&z[d], w);
}

// ---------- init output rows with bias ----------
__global__ void k_init_bias(float* __restrict__ out, const float* __restrict__ bias, int C) {
    int t = blockIdx.x * blockDim.x + threadIdx.x;
    if (t < NN * C) out[t] = bias[t % C];
}

// ---------- aggregation: out[dst] += alpha * xl[src] ----------
template <int C>
__global__ void k_aggr(const int* __restrict__ src, const int* __restrict__ dst,
                       const float* __restrict__ s, const float* __restrict__ z,
                       const float* __restrict__ xl, float* __restrict__ out) {
    const int wavesPerBlock = blockDim.x >> 6;
    long wid = (long)blockIdx.x * wavesPerBlock + (threadIdx.x >> 6);
    int lane = threadIdx.x & 63;
    if (wid >= EE + NN) return;
    int e = (int)wid;
    int sIdx, dIdx;
    if (e < EE) { sIdx = src[e]; dIdx = dst[e]; }
    else        { sIdx = dIdx = e - EE; }
    float alpha = s[e] / z[dIdx];
#pragma unroll
    for (int c = lane; c < C; c += 64)
        atomicAdd(&out[(size_t)dIdx * C + c], alpha * xl[(size_t)sIdx * C + c]);
}

__global__ void k_relu(float* __restrict__ a, int n) {
    int t = blockIdx.x * blockDim.x + threadIdx.x;
    if (t < n) a[t] = fmaxf(a[t], 0.0f);
}

// ---------- mean pooling per graph (batch_ids sorted) ----------
__global__ void k_pool(const float* __restrict__ h, const int* __restrict__ batch,
                       float* __restrict__ pooled) {
    int g = blockIdx.x;
    int lo = 0, hi = NN;
    while (lo < hi) { int mid = (lo + hi) >> 1; if (batch[mid] < g) lo = mid + 1; else hi = mid; }
    int start = lo;
    lo = start; hi = NN;
    while (lo < hi) { int mid = (lo + hi) >> 1; if (batch[mid] < g + 1) lo = mid + 1; else hi = mid; }
    int end = lo;
    float cnt = (float)(end - start);
    int c = threadIdx.x;
    if (c < 200) {
        float acc = 0.0f;
        for (int i = start; i < end; i++) acc += h[(size_t)i * 200 + c];
        pooled[g * 200 + c] = acc / fmaxf(cnt, 1.0f);
    }
}

// ---------- small dense layers on [G, *] ----------
__global__ void k_mlp(const float* __restrict__ X, const float* __restrict__ W,
                      const float* __restrict__ b, float* __restrict__ Y,
                      int Cin, int Cout, int do_relu) {
    int t = blockIdx.x * blockDim.x + threadIdx.x;
    if (t >= GG * Cout) return;
    int g = t / Cout, j = t - g * Cout;
    const float* xrow = X + (size_t)g * Cin;
    float acc = b[j];
    for (int k = 0; k < Cin; k++) acc += xrow[k] * W[k * Cout + j];
    if (do_relu) acc = fmaxf(acc, 0.0f);
    Y[t] = acc;
}

extern "C" void kernel_launch(void* const* d_in, const int* in_sizes, int n_in,
                              void* d_out, int out_size, void* d_ws, size_t ws_size,
                              hipStream_t stream) {
    const float* x   = (const float*)d_in[0];
    const int*   ei  = (const int*)d_in[1];
    const float* ea  = (const float*)d_in[2];
    const int*   bat = (const int*)d_in[3];
    const float* W1l = (const float*)d_in[4];  const float* b1l = (const float*)d_in[5];
    const float* W1r = (const float*)d_in[6];  const float* b1r = (const float*)d_in[7];
    const float* W1e = (const float*)d_in[8];
    const float* a1  = (const float*)d_in[9];  const float* c1  = (const float*)d_in[10];
    const float* W2l = (const float*)d_in[11]; const float* b2l = (const float*)d_in[12];
    const float* W2r = (const float*)d_in[13]; const float* b2r = (const float*)d_in[14];
    const float* W2e = (const float*)d_in[15];
    const float* a2  = (const float*)d_in[16]; const float* c2  = (const float*)d_in[17];
    const float* W3  = (const float*)d_in[18]; const float* b3  = (const float*)d_in[19];
    const float* F1  = (const float*)d_in[20]; const float* bf1 = (const float*)d_in[21];
    const float* F2  = (const float*)d_in[22]; const float* bf2 = (const float*)d_in[23];
    const float* F3  = (const float*)d_in[24]; const float* bf3 = (const float*)d_in[25];

    const int* srcv = ei;        // edge_index[0]
    const int* dstv = ei + EE;   // edge_index[1]

    float* W = (float*)d_ws;
    size_t off = 0;
    float* deg     = W + off; off += NN;
    float* loop_ea = W + off; off += (size_t)NN * 18;
    float* xl      = W + off; off += (size_t)NN * 200;
    float* xr      = W + off; off += (size_t)NN * 200;
    float* s       = W + off; off += (size_t)(EE + NN);
    int*   mkey    = (int*)(W + off); off += NN;
    float* z       = W + off; off += NN;
    float* h1      = W + off; off += (size_t)NN * 100;
    float* h2      = W + off; off += (size_t)NN * 200;
    float* pooled  = W + off; off += (size_t)GG * 200;
    float* p400    = W + off; off += (size_t)GG * 400;
    float* y1      = W + off; off += (size_t)GG * 200;
    float* y2      = W + off; off += (size_t)GG * 100;
    (void)ws_size; (void)n_in; (void)in_sizes; (void)out_size;

    const int B = 256;
    const int totalE = EE + NN;
    const int waveBlocks = (totalE + 3) / 4;   // 4 waves / 256-thread block

    // self-loop edge attr (mean of incoming)
    hipMemsetAsync(deg, 0, (size_t)(NN + NN * 18) * sizeof(float), stream); // deg + loop_ea
    k_deg<<<(EE + B - 1) / B, B, 0, stream>>>(dstv, deg);
    k_loopacc<<<(EE * 18 + B - 1) / B, B, 0, stream>>>(dstv, ea, loop_ea);
    k_loopdiv<<<(NN * 18 + B - 1) / B, B, 0, stream>>>(loop_ea, deg);

    // ---- GAT layer 1: 16 -> 100 ----
    k_dual_linear<<<((size_t)NN * 100 + B - 1) / B, B, 0, stream>>>(x, W1l, b1l, W1r, b1r, xl, xr, 16, 100);
    k_init_nodes<<<(NN + B - 1) / B, B, 0, stream>>>(mkey, z);
    k_edge_score<100><<<waveBlocks, B, 0, stream>>>(srcv, dstv, ea, loop_ea, W1e, a1, xl, xr, s, mkey);
    k_expsum<<<(totalE + B - 1) / B, B, 0, stream>>>(dstv, mkey, s, z);
    k_init_bias<<<((size_t)NN * 100 + B - 1) / B, B, 0, stream>>>(h1, c1, 100);
    k_aggr<100><<<waveBlocks, B, 0, stream>>>(srcv, dstv, s, z, xl, h1);
    k_relu<<<((size_t)NN * 100 + B - 1) / B, B, 0, stream>>>(h1, NN * 100);

    // ---- GAT layer 2: 100 -> 200 ----
    k_dual_linear<<<((size_t)NN * 200 + B - 1) / B, B, 0, stream>>>(h1, W2l, b2l, W2r, b2r, xl, xr, 100, 200);
    k_init_nodes<<<(NN + B - 1) / B, B, 0, stream>>>(mkey, z);
    k_edge_score<200><<<waveBlocks, B, 0, stream>>>(srcv, dstv, ea, loop_ea, W2e, a2, xl, xr, s, mkey);
    k_expsum<<<(totalE + B - 1) / B, B, 0, stream>>>(dstv, mkey, s, z);
    k_init_bias<<<((size_t)NN * 200 + B - 1) / B, B, 0, stream>>>(h2, c2, 200);
    k_aggr<200><<<waveBlocks, B, 0, stream>>>(srcv, dstv, s, z, xl, h2);
    k_relu<<<((size_t)NN * 200 + B - 1) / B, B, 0, stream>>>(h2, NN * 200);

    // ---- pool (mean over graph) then W3 folded after pooling ----
    k_pool<<<GG, 256, 0, stream>>>(h2, bat, pooled);
    k_mlp<<<(GG * 400 + B - 1) / B, B, 0, stream>>>(pooled, W3, b3, p400, 200, 400, 0);
    k_mlp<<<(GG * 200 + B - 1) / B, B, 0, stream>>>(p400, F1, bf1, y1, 400, 200, 1);
    k_mlp<<<(GG * 100 + B - 1) / B, B, 0, stream>>>(y1, F2, bf2, y2, 200, 100, 1);
    k_mlp<<<(GG * 100 + B - 1) / B, B, 0, stream>>>(y2, F3, bf3, (float*)d_out, 100, 100, 0);
}

// Round 2
// 4534.586 us; speedup vs baseline: 1.2948x; 1.2948x over previous
//
#include <hip/hip_runtime.h>
#include <cstdint>
#include <climits>

#define NN 50000
#define EE 1600000
#define TOTE (EE + NN)
#define GG 512
#define NEG_SLOPE 0.2f

// ---------- helpers ----------
__device__ __forceinline__ int f2key(float f) {
    int i = __float_as_int(f);
    return i >= 0 ? i : (i ^ 0x7fffffff);
}
__device__ __forceinline__ float key2f(int k) {
    return __int_as_float(k >= 0 ? k : (k ^ 0x7fffffff));
}

// ---------- self-loop edge_attr accumulation + degree (wave per edge) ----------
__global__ void k_loop_build(const int* __restrict__ dst, const float* __restrict__ ea,
                             float* __restrict__ loop_ea, float* __restrict__ deg) {
    int lane = threadIdx.x & 63;
    int wid = blockIdx.x * (blockDim.x >> 6) + (threadIdx.x >> 6);
    int nw = gridDim.x * (blockDim.x >> 6);
    for (int e0 = wid; e0 < EE; e0 += nw) {
        int e = __builtin_amdgcn_readfirstlane(e0);
        int d = __builtin_amdgcn_readfirstlane(dst[e]);
        if (lane < 18) atomicAdd(&loop_ea[(size_t)d * 18 + lane], ea[(size_t)e * 18 + lane]);
        else if (lane == 18) atomicAdd(&deg[d], 1.0f);
    }
}

__global__ void k_loopdiv(float* __restrict__ loop_ea, const float* __restrict__ deg) {
    int t = blockIdx.x * blockDim.x + threadIdx.x;
    if (t < NN * 18) {
        int i = t / 18;
        loop_ea[t] /= fmaxf(deg[i], 1.0f);
    }
}

// ---------- fused dual node-linear: xl = X@Wl+bl ; xr = X@Wr+br ----------
__global__ void k_dual_linear(const float* __restrict__ X,
                              const float* __restrict__ Wl, const float* __restrict__ bl,
                              const float* __restrict__ Wr, const float* __restrict__ br,
                              float* __restrict__ xl, float* __restrict__ xr,
                              int Cin, int Cout) {
    int t = blockIdx.x * blockDim.x + threadIdx.x;
    if (t >= NN * Cout) return;
    int i = t / Cout, j = t - i * Cout;
    const float* xrow = X + (size_t)i * Cin;
    float al = bl[j], ar = br[j];
    for (int k = 0; k < Cin; k++) {
        float xv = xrow[k];
        al += xv * Wl[k * Cout + j];
        ar += xv * Wr[k * Cout + j];
    }
    xl[t] = al;
    xr[t] = ar;
}

// ---------- per-node init for softmax state ----------
__global__ void k_init_nodes(int* __restrict__ mkey, float* __restrict__ z) {
    int i = blockIdx.x * blockDim.x + threadIdx.x;
    if (i < NN) { mkey[i] = INT_MIN; z[i] = 0.0f; }
}

// ---------- edge scores: s_e = att . leakyrelu(xl[src]+xr[dst]+ea@We) ----------
// Wave per edge; lane l owns channels [l*VEC, l*VEC+VEC); We columns live in VGPRs;
// edge index is wave-uniform -> ea/src/dst come through the scalar pipe.
template <int C, int VEC>
__global__ void k_edge_score(const int* __restrict__ src, const int* __restrict__ dst,
                             const float* __restrict__ ea, const float* __restrict__ loop_ea,
                             const float* __restrict__ We, const float* __restrict__ att,
                             const float* __restrict__ xl, const float* __restrict__ xr,
                             float* __restrict__ s, int* __restrict__ mkey) {
    constexpr int NL = C / VEC;  // active lanes (50 for both configs)
    int lane = threadIdx.x & 63;
    int wid = blockIdx.x * (blockDim.x >> 6) + (threadIdx.x >> 6);
    int nw = gridDim.x * (blockDim.x >> 6);

    float Wf[18][VEC];
    float af[VEC];
    if (lane < NL) {
#pragma unroll
        for (int k = 0; k < 18; k++)
#pragma unroll
            for (int j = 0; j < VEC; j++) Wf[k][j] = We[k * C + lane * VEC + j];
#pragma unroll
        for (int j = 0; j < VEC; j++) af[j] = att[lane * VEC + j];
    }

    for (int e0 = wid; e0 < TOTE; e0 += nw) {
        int e = __builtin_amdgcn_readfirstlane(e0);
        int sIdx, dIdx;
        const float* eap;
        if (e < EE) {
            sIdx = __builtin_amdgcn_readfirstlane(src[e]);
            dIdx = __builtin_amdgcn_readfirstlane(dst[e]);
            eap = ea + (size_t)e * 18;
        } else {
            sIdx = dIdx = e - EE;
            eap = loop_ea + (size_t)(e - EE) * 18;
        }
        float ee[18];
#pragma unroll
        for (int k = 0; k < 18; k++) ee[k] = eap[k];

        float part = 0.0f;
        if (lane < NL) {
            const float* xlp = xl + (size_t)sIdx * C + lane * VEC;
            const float* xrp = xr + (size_t)dIdx * C + lane * VEC;
            float u[VEC];
#pragma unroll
            for (int j = 0; j < VEC; j++) u[j] = xlp[j] + xrp[j];
#pragma unroll
            for (int k = 0; k < 18; k++)
#pragma unroll
                for (int j = 0; j < VEC; j++) u[j] += ee[k] * Wf[k][j];
#pragma unroll
            for (int j = 0; j < VEC; j++) {
                float h = u[j] > 0.0f ? u[j] : NEG_SLOPE * u[j];
                part += af[j] * h;
            }
        }
#pragma unroll
        for (int off = 32; off; off >>= 1) part += __shfl_xor(part, off, 64);
        if (lane == 0) {
            s[e] = part;
            atomicMax(&mkey[dIdx], f2key(part));
        }
    }
}

// ---------- exp(s - m[dst]) and z accumulation ----------
__global__ void k_expsum(const int* __restrict__ dst, const int* __restrict__ mkey,
                         float* __restrict__ s, float* __restrict__ z) {
    int e = blockIdx.x * blockDim.x + threadIdx.x;
    if (e >= TOTE) return;
    int d = (e < EE) ? dst[e] : (e - EE);
    float m = key2f(mkey[d]);
    float w = expf(s[e] - m);
    s[e] = w;
    atomicAdd(&z[d], w);
}

// ---------- init output rows with bias ----------
template <int C>
__global__ void k_init_bias(float* __restrict__ out, const float* __restrict__ bias) {
    int t = blockIdx.x * blockDim.x + threadIdx.x;
    if (t < NN * C) out[t] = bias[t % C];
}

// ---------- aggregation: out[dst] += alpha * xl[src]  (wave per edge) ----------
template <int C>
__global__ void k_aggr(const int* __restrict__ src, const int* __restrict__ dst,
                       const float* __restrict__ s, const float* __restrict__ z,
                       const float* __restrict__ xl, float* __restrict__ out) {
    int lane = threadIdx.x & 63;
    int wid = blockIdx.x * (blockDim.x >> 6) + (threadIdx.x >> 6);
    int nw = gridDim.x * (blockDim.x >> 6);
    for (int e0 = wid; e0 < TOTE; e0 += nw) {
        int e = __builtin_amdgcn_readfirstlane(e0);
        int sIdx, dIdx;
        if (e < EE) {
            sIdx = __builtin_amdgcn_readfirstlane(src[e]);
            dIdx = __builtin_amdgcn_readfirstlane(dst[e]);
        } else {
            sIdx = dIdx = e - EE;
        }
        float alpha = s[e] / z[dIdx];
        const float* xp = xl + (size_t)sIdx * C;
        float* op = out + (size_t)dIdx * C;
#pragma unroll
        for (int c = lane; c < C; c += 64) atomicAdd(&op[c], alpha * xp[c]);
    }
}

__global__ void k_relu(float* __restrict__ a, int n) {
    int t = blockIdx.x * blockDim.x + threadIdx.x;
    if (t < n) a[t] = fmaxf(a[t], 0.0f);
}

// ---------- mean pooling per graph (batch_ids sorted); relu folded in ----------
__global__ void k_pool(const float* __restrict__ h, const int* __restrict__ batch,
                       float* __restrict__ pooled) {
    int g = blockIdx.x;
    int lo = 0, hi = NN;
    while (lo < hi) { int mid = (lo + hi) >> 1; if (batch[mid] < g) lo = mid + 1; else hi = mid; }
    int start = lo;
    lo = start; hi = NN;
    while (lo < hi) { int mid = (lo + hi) >> 1; if (batch[mid] < g + 1) lo = mid + 1; else hi = mid; }
    int end = lo;
    float cnt = (float)(end - start);
    int c = threadIdx.x;
    if (c < 200) {
        float acc = 0.0f;
        for (int i = start; i < end; i++) acc += fmaxf(h[(size_t)i * 200 + c], 0.0f);
        pooled[g * 200 + c] = acc / fmaxf(cnt, 1.0f);
    }
}

// ---------- small dense layers on [G, *] ----------
__global__ void k_mlp(const float* __restrict__ X, const float* __restrict__ W,
                      const float* __restrict__ b, float* __restrict__ Y,
                      int Cin, int Cout, int do_relu) {
    int t = blockIdx.x * blockDim.x + threadIdx.x;
    if (t >= GG * Cout) return;
    int g = t / Cout, j = t - g * Cout;
    const float* xrow = X + (size_t)g * Cin;
    float acc = b[j];
    for (int k = 0; k < Cin; k++) acc += xrow[k] * W[k * Cout + j];
    if (do_relu) acc = fmaxf(acc, 0.0f);
    Y[t] = acc;
}

extern "C" void kernel_launch(void* const* d_in, const int* in_sizes, int n_in,
                              void* d_out, int out_size, void* d_ws, size_t ws_size,
                              hipStream_t stream) {
    const float* x   = (const float*)d_in[0];
    const int*   ei  = (const int*)d_in[1];
    const float* ea  = (const float*)d_in[2];
    const int*   bat = (const int*)d_in[3];
    const float* W1l = (const float*)d_in[4];  const float* b1l = (const float*)d_in[5];
    const float* W1r = (const float*)d_in[6];  const float* b1r = (const float*)d_in[7];
    const float* W1e = (const float*)d_in[8];
    const float* a1  = (const float*)d_in[9];  const float* c1  = (const float*)d_in[10];
    const float* W2l = (const float*)d_in[11]; const float* b2l = (const float*)d_in[12];
    const float* W2r = (const float*)d_in[13]; const float* b2r = (const float*)d_in[14];
    const float* W2e = (const float*)d_in[15];
    const float* a2  = (const float*)d_in[16]; const float* c2  = (const float*)d_in[17];
    const float* W3  = (const float*)d_in[18]; const float* b3  = (const float*)d_in[19];
    const float* F1  = (const float*)d_in[20]; const float* bf1 = (const float*)d_in[21];
    const float* F2  = (const float*)d_in[22]; const float* bf2 = (const float*)d_in[23];
    const float* F3  = (const float*)d_in[24]; const float* bf3 = (const float*)d_in[25];

    const int* srcv = ei;        // edge_index[0]
    const int* dstv = ei + EE;   // edge_index[1]

    float* W = (float*)d_ws;
    size_t off = 0;
    float* deg     = W + off; off += NN;
    float* loop_ea = W + off; off += (size_t)NN * 18;
    float* xl      = W + off; off += (size_t)NN * 200;
    float* xr      = W + off; off += (size_t)NN * 200;
    float* s       = W + off; off += (size_t)TOTE;
    int*   mkey    = (int*)(W + off); off += NN;
    float* z       = W + off; off += NN;
    float* h1      = W + off; off += (size_t)NN * 100;
    float* h2      = W + off; off += (size_t)NN * 200;
    float* pooled  = W + off; off += (size_t)GG * 200;
    float* p400    = W + off; off += (size_t)GG * 400;
    float* y1      = W + off; off += (size_t)GG * 200;
    float* y2      = W + off; off += (size_t)GG * 100;
    (void)ws_size; (void)n_in; (void)in_sizes; (void)out_size;

    const int B = 256;
    const int PERS = 1280;   // persistent blocks (4 waves each) for wave-per-edge kernels

    // self-loop edge attr (mean of incoming)
    hipMemsetAsync(deg, 0, (size_t)(NN + NN * 18) * sizeof(float), stream); // deg + loop_ea
    k_loop_build<<<PERS, B, 0, stream>>>(dstv, ea, loop_ea, deg);
    k_loopdiv<<<(NN * 18 + B - 1) / B, B, 0, stream>>>(loop_ea, deg);

    // ---- GAT layer 1: 16 -> 100 ----
    k_dual_linear<<<((size_t)NN * 100 + B - 1) / B, B, 0, stream>>>(x, W1l, b1l, W1r, b1r, xl, xr, 16, 100);
    k_init_nodes<<<(NN + B - 1) / B, B, 0, stream>>>(mkey, z);
    k_edge_score<100, 2><<<PERS, B, 0, stream>>>(srcv, dstv, ea, loop_ea, W1e, a1, xl, xr, s, mkey);
    k_expsum<<<(TOTE + B - 1) / B, B, 0, stream>>>(dstv, mkey, s, z);
    k_init_bias<100><<<((size_t)NN * 100 + B - 1) / B, B, 0, stream>>>(h1, c1);
    k_aggr<100><<<PERS, B, 0, stream>>>(srcv, dstv, s, z, xl, h1);
    k_relu<<<((size_t)NN * 100 + B - 1) / B, B, 0, stream>>>(h1, NN * 100);

    // ---- GAT layer 2: 100 -> 200 ----
    k_dual_linear<<<((size_t)NN * 200 + B - 1) / B, B, 0, stream>>>(h1, W2l, b2l, W2r, b2r, xl, xr, 100, 200);
    k_init_nodes<<<(NN + B - 1) / B, B, 0, stream>>>(mkey, z);
    k_edge_score<200, 4><<<PERS, B, 0, stream>>>(srcv, dstv, ea, loop_ea, W2e, a2, xl, xr, s, mkey);
    k_expsum<<<(TOTE + B - 1) / B, B, 0, stream>>>(dstv, mkey, s, z);
    k_init_bias<200><<<((size_t)NN * 200 + B - 1) / B, B, 0, stream>>>(h2, c2);
    k_aggr<200><<<PERS, B, 0, stream>>>(srcv, dstv, s, z, xl, h2);
    // relu for h2 folded into k_pool

    // ---- pool (mean over graph) then W3 folded after pooling ----
    k_pool<<<GG, 256, 0, stream>>>(h2, bat, pooled);
    k_mlp<<<(GG * 400 + B - 1) / B, B, 0, stream>>>(pooled, W3, b3, p400, 200, 400, 0);
    k_mlp<<<(GG * 200 + B - 1) / B, B, 0, stream>>>(p400, F1, bf1, y1, 400, 200, 1);
    k_mlp<<<(GG * 100 + B - 1) / B, B, 0, stream>>>(y1, F2, bf2, y2, 200, 100, 1);
    k_mlp<<<(GG * 100 + B - 1) / B, B, 0, stream>>>(y2, F3, bf3, (float*)d_out, 100, 100, 0);
}

// Round 3
// 3332.832 us; speedup vs baseline: 1.7617x; 1.3606x over previous
//
#include <hip/hip_runtime.h>
#include <cstdint>
#include <climits>
#include <math.h>

#define NN 50000
#define EE 1600000
#define TOTE (EE + NN)
#define GG 512
#define NEG_SLOPE 0.2f
#define NB 196          // ceil(NN/256) scan blocks

// ---------- self-loop edge_attr accumulation + degree (wave per edge) ----------
__global__ void k_loop_build(const int* __restrict__ dst, const float* __restrict__ ea,
                             float* __restrict__ loop_ea, int* __restrict__ hist) {
    int lane = threadIdx.x & 63;
    int wid = blockIdx.x * (blockDim.x >> 6) + (threadIdx.x >> 6);
    int nw = gridDim.x * (blockDim.x >> 6);
    for (int e0 = wid; e0 < EE; e0 += nw) {
        int e = __builtin_amdgcn_readfirstlane(e0);
        int d = __builtin_amdgcn_readfirstlane(dst[e]);
        if (lane < 18) atomicAdd(&loop_ea[(size_t)d * 18 + lane], ea[(size_t)e * 18 + lane]);
        else if (lane == 18) atomicAdd(&hist[d], 1);
    }
}

__global__ void k_loopdiv(float* __restrict__ loop_ea, const int* __restrict__ hist) {
    int t = blockIdx.x * blockDim.x + threadIdx.x;
    if (t < NN * 18) {
        int i = t / 18;
        loop_ea[t] /= fmaxf((float)hist[i], 1.0f);
    }
}

// ---------- CSR build: scan of (hist[i]+1) then scatter ----------
__global__ void k_scan_a(const int* __restrict__ hist, int* __restrict__ bsum) {
    __shared__ int tmp[256];
    int i = blockIdx.x * 256 + threadIdx.x;
    tmp[threadIdx.x] = (i < NN) ? (hist[i] + 1) : 0;
    __syncthreads();
    for (int d = 128; d; d >>= 1) {
        if (threadIdx.x < d) tmp[threadIdx.x] += tmp[threadIdx.x + d];
        __syncthreads();
    }
    if (threadIdx.x == 0) bsum[blockIdx.x] = tmp[0];
}

__global__ void k_scan_b(int* __restrict__ bsum, int* __restrict__ rowptr) {
    // single thread: exclusive scan over NB block sums
    int acc = 0;
    for (int b = 0; b < NB; b++) { int v = bsum[b]; bsum[b] = acc; acc += v; }
    rowptr[NN] = acc;  // == TOTE
}

__global__ void k_scan_c(const int* __restrict__ hist, const int* __restrict__ bsum,
                         int* __restrict__ rowptr) {
    __shared__ int tmp[256];
    int i = blockIdx.x * 256 + threadIdx.x;
    int v = (i < NN) ? (hist[i] + 1) : 0;
    tmp[threadIdx.x] = v;
    __syncthreads();
    for (int d = 1; d < 256; d <<= 1) {
        int t = (threadIdx.x >= d) ? tmp[threadIdx.x - d] : 0;
        __syncthreads();
        tmp[threadIdx.x] += t;
        __syncthreads();
    }
    if (i < NN) rowptr[i] = tmp[threadIdx.x] - v + bsum[blockIdx.x];
}

__global__ void k_cursor_init(const int* __restrict__ rowptr, int* __restrict__ cursor,
                              int* __restrict__ csr_eid) {
    int i = blockIdx.x * blockDim.x + threadIdx.x;
    if (i < NN) {
        int base = rowptr[i];
        csr_eid[base] = EE + i;   // self-loop first
        cursor[i] = base + 1;
    }
}

__global__ void k_scatter(const int* __restrict__ dst, int* __restrict__ cursor,
                          int* __restrict__ csr_eid) {
    int e = blockIdx.x * blockDim.x + threadIdx.x;
    if (e < EE) {
        int p = atomicAdd(&cursor[dst[e]], 1);
        csr_eid[p] = e;
    }
}

// ---------- fused dual node-linear: xl = X@Wl+bl ; xr = X@Wr+br ----------
__global__ void k_dual_linear(const float* __restrict__ X,
                              const float* __restrict__ Wl, const float* __restrict__ bl,
                              const float* __restrict__ Wr, const float* __restrict__ br,
                              float* __restrict__ xl, float* __restrict__ xr,
                              int Cin, int Cout) {
    int t = blockIdx.x * blockDim.x + threadIdx.x;
    if (t >= NN * Cout) return;
    int i = t / Cout, j = t - i * Cout;
    const float* xrow = X + (size_t)i * Cin;
    float al = bl[j], ar = br[j];
    for (int k = 0; k < Cin; k++) {
        float xv = xrow[k];
        al += xv * Wl[k * Cout + j];
        ar += xv * Wr[k * Cout + j];
    }
    xl[t] = al;
    xr[t] = ar;
}

// ---------- edge scores: s_e = att . leakyrelu(xl[src]+xr[dst]+ea@We) ----------
template <int C, int VEC>
__global__ void k_edge_score(const int* __restrict__ src, const int* __restrict__ dst,
                             const float* __restrict__ ea, const float* __restrict__ loop_ea,
                             const float* __restrict__ We, const float* __restrict__ att,
                             const float* __restrict__ xl, const float* __restrict__ xr,
                             float* __restrict__ s) {
    constexpr int NL = C / VEC;
    int lane = threadIdx.x & 63;
    int wid = blockIdx.x * (blockDim.x >> 6) + (threadIdx.x >> 6);
    int nw = gridDim.x * (blockDim.x >> 6);

    float Wf[18][VEC];
    float af[VEC];
    if (lane < NL) {
#pragma unroll
        for (int k = 0; k < 18; k++)
#pragma unroll
            for (int j = 0; j < VEC; j++) Wf[k][j] = We[k * C + lane * VEC + j];
#pragma unroll
        for (int j = 0; j < VEC; j++) af[j] = att[lane * VEC + j];
    }

    for (int e0 = wid; e0 < TOTE; e0 += nw) {
        int e = __builtin_amdgcn_readfirstlane(e0);
        int sIdx, dIdx;
        const float* eap;
        if (e < EE) {
            sIdx = __builtin_amdgcn_readfirstlane(src[e]);
            dIdx = __builtin_amdgcn_readfirstlane(dst[e]);
            eap = ea + (size_t)e * 18;
        } else {
            sIdx = dIdx = e - EE;
            eap = loop_ea + (size_t)(e - EE) * 18;
        }
        float ee[18];
#pragma unroll
        for (int k = 0; k < 18; k++) ee[k] = eap[k];

        float part = 0.0f;
        if (lane < NL) {
            const float* xlp = xl + (size_t)sIdx * C + lane * VEC;
            const float* xrp = xr + (size_t)dIdx * C + lane * VEC;
            float u[VEC];
#pragma unroll
            for (int j = 0; j < VEC; j++) u[j] = xlp[j] + xrp[j];
#pragma unroll
            for (int k = 0; k < 18; k++)
#pragma unroll
                for (int j = 0; j < VEC; j++) u[j] += ee[k] * Wf[k][j];
#pragma unroll
            for (int j = 0; j < VEC; j++) {
                float h = u[j] > 0.0f ? u[j] : NEG_SLOPE * u[j];
                part += af[j] * h;
            }
        }
#pragma unroll
        for (int off = 32; off; off >>= 1) part += __shfl_xor(part, off, 64);
        if (lane == 0) s[e] = part;
    }
}

// ---------- per-dst-node softmax + aggregate + bias (+relu), no atomics ----------
// Wave per node; lane l (< C/4) owns channels [4l, 4l+4) as a float4.
template <int C, int RELU>
__global__ void k_node_aggr(const int* __restrict__ rowptr, const int* __restrict__ csr_eid,
                            const int* __restrict__ srcv, const float* __restrict__ s,
                            const float* __restrict__ xl, const float* __restrict__ bias,
                            float* __restrict__ out) {
    constexpr int NL = C / 4;
    int lane = threadIdx.x & 63;
    int wid = blockIdx.x * (blockDim.x >> 6) + (threadIdx.x >> 6);
    int nw = gridDim.x * (blockDim.x >> 6);

    float4 bv = make_float4(0.f, 0.f, 0.f, 0.f);
    if (lane < NL) bv = ((const float4*)bias)[lane];

    for (int i = wid; i < NN; i += nw) {
        int beg = rowptr[i], end = rowptr[i + 1];
        // pass 1: online max + expsum (wave-uniform scalar work)
        float m = -INFINITY, zs = 0.0f;
        for (int p = beg; p < end; p++) {
            float sv = s[csr_eid[p]];
            if (sv > m) { zs *= __expf(m - sv); m = sv; }
            zs += __expf(sv - m);
        }
        float rz = 1.0f / zs;
        // pass 2: weighted gather-accumulate
        float4 acc = bv;
        for (int p = beg; p < end; p++) {
            int eid = csr_eid[p];
            float alpha = __expf(s[eid] - m) * rz;
            int srcI = (eid < EE) ? srcv[eid] : i;
            if (lane < NL) {
                float4 xv = ((const float4*)xl)[(size_t)srcI * NL + lane];
                acc.x += alpha * xv.x;
                acc.y += alpha * xv.y;
                acc.z += alpha * xv.z;
                acc.w += alpha * xv.w;
            }
        }
        if (lane < NL) {
            if (RELU) {
                acc.x = fmaxf(acc.x, 0.f); acc.y = fmaxf(acc.y, 0.f);
                acc.z = fmaxf(acc.z, 0.f); acc.w = fmaxf(acc.w, 0.f);
            }
            ((float4*)out)[(size_t)i * NL + lane] = acc;
        }
    }
}

// ---------- mean pooling per graph (batch_ids sorted); relu folded in ----------
__global__ void k_pool(const float* __restrict__ h, const int* __restrict__ batch,
                       float* __restrict__ pooled) {
    int g = blockIdx.x;
    int lo = 0, hi = NN;
    while (lo < hi) { int mid = (lo + hi) >> 1; if (batch[mid] < g) lo = mid + 1; else hi = mid; }
    int start = lo;
    lo = start; hi = NN;
    while (lo < hi) { int mid = (lo + hi) >> 1; if (batch[mid] < g + 1) lo = mid + 1; else hi = mid; }
    int end = lo;
    float cnt = (float)(end - start);
    int c = threadIdx.x;
    if (c < 200) {
        float acc = 0.0f;
        for (int i = start; i < end; i++) acc += fmaxf(h[(size_t)i * 200 + c], 0.0f);
        pooled[g * 200 + c] = acc / fmaxf(cnt, 1.0f);
    }
}

// ---------- small dense layers on [G, *] ----------
__global__ void k_mlp(const float* __restrict__ X, const float* __restrict__ W,
                      const float* __restrict__ b, float* __restrict__ Y,
                      int Cin, int Cout, int do_relu) {
    int t = blockIdx.x * blockDim.x + threadIdx.x;
    if (t >= GG * Cout) return;
    int g = t / Cout, j = t - g * Cout;
    const float* xrow = X + (size_t)g * Cin;
    float acc = b[j];
    for (int k = 0; k < Cin; k++) acc += xrow[k] * W[k * Cout + j];
    if (do_relu) acc = fmaxf(acc, 0.0f);
    Y[t] = acc;
}

extern "C" void kernel_launch(void* const* d_in, const int* in_sizes, int n_in,
                              void* d_out, int out_size, void* d_ws, size_t ws_size,
                              hipStream_t stream) {
    const float* x   = (const float*)d_in[0];
    const int*   ei  = (const int*)d_in[1];
    const float* ea  = (const float*)d_in[2];
    const int*   bat = (const int*)d_in[3];
    const float* W1l = (const float*)d_in[4];  const float* b1l = (const float*)d_in[5];
    const float* W1r = (const float*)d_in[6];  const float* b1r = (const float*)d_in[7];
    const float* W1e = (const float*)d_in[8];
    const float* a1  = (const float*)d_in[9];  const float* c1  = (const float*)d_in[10];
    const float* W2l = (const float*)d_in[11]; const float* b2l = (const float*)d_in[12];
    const float* W2r = (const float*)d_in[13]; const float* b2r = (const float*)d_in[14];
    const float* W2e = (const float*)d_in[15];
    const float* a2  = (const float*)d_in[16]; const float* c2  = (const float*)d_in[17];
    const float* W3  = (const float*)d_in[18]; const float* b3  = (const float*)d_in[19];
    const float* F1  = (const float*)d_in[20]; const float* bf1 = (const float*)d_in[21];
    const float* F2  = (const float*)d_in[22]; const float* bf2 = (const float*)d_in[23];
    const float* F3  = (const float*)d_in[24]; const float* bf3 = (const float*)d_in[25];

    const int* srcv = ei;        // edge_index[0]
    const int* dstv = ei + EE;   // edge_index[1]

    float* W = (float*)d_ws;
    size_t off = 0;
    int*   hist    = (int*)(W + off); off += NN;               // 16B-aligned chunks
    float* loop_ea = W + off; off += (size_t)NN * 18;
    float* xl      = W + off; off += (size_t)NN * 200;
    float* xr      = W + off; off += (size_t)NN * 200;
    float* s       = W + off; off += (size_t)TOTE;
    float* h1      = W + off; off += (size_t)NN * 100;
    float* h2      = W + off; off += (size_t)NN * 200;
    int*   rowptr  = (int*)(W + off); off += NN + 4;
    int*   cursor  = (int*)(W + off); off += NN;
    int*   csr_eid = (int*)(W + off); off += TOTE;
    int*   bsum    = (int*)(W + off); off += 256;
    float* pooled  = W + off; off += (size_t)GG * 200;
    float* p400    = W + off; off += (size_t)GG * 400;
    float* y1      = W + off; off += (size_t)GG * 200;
    float* y2      = W + off; off += (size_t)GG * 100;
    (void)ws_size; (void)n_in; (void)in_sizes; (void)out_size;

    const int B = 256;
    const int PERS = 1280;     // persistent blocks for wave-per-edge kernels
    const int NODEB = 12500;   // 4 waves/block -> 50000 waves, 1 node each

    // ---- self-loop edge attr (mean of incoming) + degree histogram ----
    hipMemsetAsync(hist, 0, (size_t)(NN + (size_t)NN * 18) * sizeof(float), stream); // hist + loop_ea
    k_loop_build<<<PERS, B, 0, stream>>>(dstv, ea, loop_ea, hist);
    k_loopdiv<<<(NN * 18 + B - 1) / B, B, 0, stream>>>(loop_ea, hist);

    // ---- CSR by dst (self-loop in slot rowptr[i]) ----
    k_scan_a<<<NB, 256, 0, stream>>>(hist, bsum);
    k_scan_b<<<1, 1, 0, stream>>>(bsum, rowptr);
    k_scan_c<<<NB, 256, 0, stream>>>(hist, bsum, rowptr);
    k_cursor_init<<<(NN + B - 1) / B, B, 0, stream>>>(rowptr, cursor, csr_eid);
    k_scatter<<<(EE + B - 1) / B, B, 0, stream>>>(dstv, cursor, csr_eid);

    // ---- GAT layer 1: 16 -> 100 ----
    k_dual_linear<<<((size_t)NN * 100 + B - 1) / B, B, 0, stream>>>(x, W1l, b1l, W1r, b1r, xl, xr, 16, 100);
    k_edge_score<100, 2><<<PERS, B, 0, stream>>>(srcv, dstv, ea, loop_ea, W1e, a1, xl, xr, s);
    k_node_aggr<100, 1><<<NODEB, B, 0, stream>>>(rowptr, csr_eid, srcv, s, xl, c1, h1);

    // ---- GAT layer 2: 100 -> 200 ----
    k_dual_linear<<<((size_t)NN * 200 + B - 1) / B, B, 0, stream>>>(h1, W2l, b2l, W2r, b2r, xl, xr, 100, 200);
    k_edge_score<200, 4><<<PERS, B, 0, stream>>>(srcv, dstv, ea, loop_ea, W2e, a2, xl, xr, s);
    k_node_aggr<200, 0><<<NODEB, B, 0, stream>>>(rowptr, csr_eid, srcv, s, xl, c2, h2);

    // ---- pool (mean over graph, relu fused) then W3 + FFN ----
    k_pool<<<GG, 256, 0, stream>>>(h2, bat, pooled);
    k_mlp<<<(GG * 400 + B - 1) / B, B, 0, stream>>>(pooled, W3, b3, p400, 200, 400, 0);
    k_mlp<<<(GG * 200 + B - 1) / B, B, 0, stream>>>(p400, F1, bf1, y1, 400, 200, 1);
    k_mlp<<<(GG * 100 + B - 1) / B, B, 0, stream>>>(y1, F2, bf2, y2, 200, 100, 1);
    k_mlp<<<(GG * 100 + B - 1) / B, B, 0, stream>>>(y2, F3, bf3, (float*)d_out, 100, 100, 0);
}